// Round 1
// 428.709 us; speedup vs baseline: 1.7926x; 1.7926x over previous
//
#include <hip/hip_runtime.h>

// VQ-VAE vector quantizer, MI355X (gfx950).
// Round 6:
//  (a) pass-A upgraded to 3-MFMA bf16: z split hi+lo, codebook split hi+lo;
//      acc = zl*ch + zh*ch + zh*cl. Residual terms (zl*cl, 2^-18 splits, fp32
//      MFMA accum rounding) bound dot err ~<5e-6. The margin floor is the
//      reference emulation's own fp32 rounding at |d|~256: 2*ulp(256)=6.1e-5.
//      MARGIN 4e-4 -> 1.0e-4  (flag count ~5400 -> ~1400).
//  (b) fixup rewritten wave-per-code: 64 lanes cooperatively dot ONE code row
//      (coalesced 1KB load per code, fp64 butterfly reduce, z-row in regs).
//      Old layout (4 strided rows per thread) thrashed L1 and was L2-bound at
//      ~570us; new form moves exactly 1MB/row through L2.
//
// d_out (float32): [0,16777216) quantized; [16777216,16842752) codes; [16842752] vq_loss
//   (bytes [0, 1048576) of d_out double as cbh_perm/cbl_perm scratch until gather overwrites)
// d_ws: [0,2048) double loss_slots[256]; [2048,2052) int flag_count;
//       [4096,8192) float Bf[1024]; [8192,270336) int flag_list[65536]

#define N_PTS    65536
#define K_CODES  1024
#define DIM      256
#define MARGIN   1.0e-4f

#define OUT_VALS  16777216
#define OUT_CODES 65536

typedef __attribute__((ext_vector_type(8))) short short8v;
typedef __attribute__((ext_vector_type(4))) float float4v;

__device__ __forceinline__ short f2bf(float x) {
  union { float f; unsigned u; } v; v.f = x;
  unsigned r = v.u + 0x7fff + ((v.u >> 16) & 1);   // RTN-even
  return (short)(r >> 16);
}
__device__ __forceinline__ float bf2f(short h) {
  union { unsigned u; float f; } v; v.u = ((unsigned)(unsigned short)h) << 16;
  return v.f;
}

// perm index (in shorts) for codebook element (r, k):
// chunk = ((r>>4)*8 + (k>>5))*4 + ((k>>3)&3); idx = chunk*128 + (r&15)*8 + (k&7)
__device__ __forceinline__ int perm_idx(int r, int k) {
  return ((((r >> 4) * 8 + (k >> 5)) * 4 + ((k >> 3) & 3)) * 128) + (r & 15) * 8 + (k & 7);
}

// one wave per code row: Bf[r] = fl32(fp64 sum of squares); also emit bf16
// hi AND lo codebook splits in B-fragment-permuted order. grid 256 x 256.
__global__ void prep_cb_kernel(const float* __restrict__ cb,
                               short* __restrict__ cbh_perm,
                               short* __restrict__ cbl_perm,
                               float* __restrict__ Bf) {
  int r    = blockIdx.x * 4 + (threadIdx.x >> 6);
  int lane = threadIdx.x & 63;
  const float4 v = *(const float4*)(cb + (size_t)r * DIM + lane * 4);
  double s = (double)v.x * v.x + (double)v.y * v.y
           + (double)v.z * v.z + (double)v.w * v.w;
#pragma unroll
  for (int off = 32; off > 0; off >>= 1) s += __shfl_down(s, off);
  if (lane == 0) Bf[r] = (float)s;
  short4 h = make_short4(f2bf(v.x), f2bf(v.y), f2bf(v.z), f2bf(v.w));
  short4 lo = make_short4(f2bf(v.x - bf2f(h.x)), f2bf(v.y - bf2f(h.y)),
                          f2bf(v.z - bf2f(h.z)), f2bf(v.w - bf2f(h.w)));
  *(short4*)(cbh_perm + perm_idx(r, lane * 4)) = h;    // (k&7)∈{0,4}: 8B aligned
  *(short4*)(cbl_perm + perm_idx(r, lane * 4)) = lo;
}

// 1024 blocks x 256 thr (4 waves). Block: 64 points x all 1024 codes.
// Wave w: 16 points. A-frags resident (hi+lo). Codes iterated 32 at a time.
__global__ __launch_bounds__(256, 4) void argmin_mfma_kernel(
    const float* __restrict__ z, const short* __restrict__ cbh_perm,
    const short* __restrict__ cbl_perm,
    const float* __restrict__ Bf, float* __restrict__ codes_out,
    int* __restrict__ flag_count, int* __restrict__ flag_list) {
  __shared__ __align__(16) short lbuf[16384];  // 32 KB: 32 codes x 256 d, hi | lo
  const int t    = threadIdx.x;
  const int w    = t >> 6;
  const int l    = t & 63;
  const int quad = l >> 4;
  const int lr   = l & 15;
  const int m0   = blockIdx.x * 64;

  // A-fragments: lane holds A[m=lr][k=q*32+quad*8+j], split bf16 hi/lo
  short8v ah[8], al[8];
  {
    const float* zrow = z + (size_t)(m0 + w * 16 + lr) * DIM;
#pragma unroll
    for (int q = 0; q < 8; ++q) {
      float4 p0 = *(const float4*)(zrow + q * 32 + quad * 8);
      float4 p1 = *(const float4*)(zrow + q * 32 + quad * 8 + 4);
      float e[8] = {p0.x, p0.y, p0.z, p0.w, p1.x, p1.y, p1.z, p1.w};
      short8v h, lo;
#pragma unroll
      for (int j = 0; j < 8; ++j) {
        short hb = f2bf(e[j]);
        h[j]  = hb;
        lo[j] = f2bf(e[j] - bf2f(hb));
      }
      ah[q] = h; al[q] = lo;
    }
  }

  float bestv[4], secv[4]; int bestk[4];
#pragma unroll
  for (int r = 0; r < 4; ++r) { bestv[r] = 3.0e38f; secv[r] = 3.0e38f; bestk[r] = 0; }

  for (int c0 = 0; c0 < K_CODES; c0 += 32) {
    __syncthreads();
    // stage 16KB hi + 16KB lo, contiguous (perm layout == LDS layout)
    const short* srch = cbh_perm + c0 * 256;
    const short* srcl = cbl_perm + c0 * 256;
#pragma unroll
    for (int i = 0; i < 4; ++i) {
      *(float4*)(lbuf + t * 8 + i * 2048) = *(const float4*)(srch + t * 8 + i * 2048);
      *(float4*)(lbuf + 8192 + t * 8 + i * 2048) = *(const float4*)(srcl + t * 8 + i * 2048);
    }
    __syncthreads();

#pragma unroll
    for (int st = 0; st < 2; ++st) {
      float4v acc = {0.f, 0.f, 0.f, 0.f};
#pragma unroll
      for (int q = 0; q < 8; ++q) {
        // B-frag: lane holds B[k=quad*8+j][n=lr] == cb[n][k] (B^T rows)
        short8v bh = *(const short8v*)(lbuf + (st * 8 + q) * 512 + quad * 128 + lr * 8);
        short8v bl = *(const short8v*)(lbuf + 8192 + (st * 8 + q) * 512 + quad * 128 + lr * 8);
        acc = __builtin_amdgcn_mfma_f32_16x16x32_bf16(al[q], bh, acc, 0, 0, 0);
        acc = __builtin_amdgcn_mfma_f32_16x16x32_bf16(ah[q], bl, acc, 0, 0, 0);
        acc = __builtin_amdgcn_mfma_f32_16x16x32_bf16(ah[q], bh, acc, 0, 0, 0);
      }
      const int k = c0 + st * 16 + lr;       // this lane's code (C col = lane&15)
      const float bk_ = Bf[k];
#pragma unroll
      for (int r = 0; r < 4; ++r) {          // C row = quad*4 + r (point)
        float v = fmaf(-2.0f, acc[r], bk_);
        bool lt  = v < bestv[r];
        secv[r]  = lt ? bestv[r] : fminf(secv[r], v);
        bestk[r] = lt ? k : bestk[r];
        bestv[r] = lt ? v : bestv[r];
      }
    }
  }

  // top-2 merge across the 16 col-lanes of each quad (butterfly)
#pragma unroll
  for (int mask = 1; mask < 16; mask <<= 1) {
#pragma unroll
    for (int r = 0; r < 4; ++r) {
      float ov = __shfl_xor(bestv[r], mask);
      float os = __shfl_xor(secv[r], mask);
      int   ok = __shfl_xor(bestk[r], mask);
      bool win = (ov < bestv[r]) || (ov == bestv[r] && ok < bestk[r]);
      float ns = win ? fminf(bestv[r], os) : fminf(secv[r], ov);
      bestv[r] = win ? ov : bestv[r];
      bestk[r] = win ? ok : bestk[r];
      secv[r]  = ns;
    }
  }
  if (lr == 0) {
#pragma unroll
    for (int r = 0; r < 4; ++r) {
      int n = m0 + w * 16 + quad * 4 + r;
      codes_out[n] = (float)bestk[r];
      if (secv[r] - bestv[r] < MARGIN) {
        int pos = atomicAdd(flag_count, 1);
        flag_list[pos] = n;
      }
    }
  }
}

// Exact re-resolution of flagged rows; one block per row (grid-stride).
// Wave-per-code: 64 lanes cooperatively dot one code row (coalesced 1KB
// loads), fp64 butterfly reduce. Emulation semantics preserved:
// v = fl32(fl32(S+B) - 2*fl32(dot64)); fp64 summation order change is
// invisible after fl32 rounding (boundary probability ~e-11 per dot).
__global__ __launch_bounds__(256) void fixup_kernel(
    const float* __restrict__ z, const float* __restrict__ cb,
    const float* __restrict__ Bf, const int* __restrict__ flag_list,
    const int* __restrict__ flag_count, float* __restrict__ codes_out) {
  __shared__ float vred[4];
  __shared__ int   kred[4];
  const int t = threadIdx.x;
  const int w = t >> 6;
  const int l = t & 63;
  const int cnt = *flag_count;
  for (int i = blockIdx.x; i < cnt; i += gridDim.x) {
    const int n = flag_list[i];
    const float4 zv = *(const float4*)(z + (size_t)n * DIM + l * 4);
    // Sfl = fl32(fp64 sum of z^2), all lanes
    double s = (double)zv.x * zv.x + (double)zv.y * zv.y
             + (double)zv.z * zv.z + (double)zv.w * zv.w;
#pragma unroll
    for (int off = 32; off > 0; off >>= 1) s += __shfl_xor(s, off);
    const float Sfl = (float)s;
    float bv = 3.0e38f; int bk = 0;
    // wave w owns codes [w*256, (w+1)*256), ascending -> '<' keeps lowest k
#pragma unroll 4
    for (int k0 = 0; k0 < 256; ++k0) {
      const int k = (w << 8) + k0;
      const float4 cv = *(const float4*)(cb + (size_t)k * DIM + l * 4);
      double d = (double)zv.x * cv.x + (double)zv.y * cv.y
               + (double)zv.z * cv.z + (double)zv.w * cv.w;
#pragma unroll
      for (int off = 32; off > 0; off >>= 1) d += __shfl_xor(d, off);
      float T1 = Sfl + Bf[k];
      float v  = T1 - 2.0f * (float)d;
      if (v < bv) { bv = v; bk = k; }
    }
    __syncthreads();                 // protect vred/kred reuse across rows
    if (l == 0) { vred[w] = bv; kred[w] = bk; }
    __syncthreads();
    if (t == 0) {
      float fv = vred[0]; int fk = kred[0];
#pragma unroll
      for (int j = 1; j < 4; ++j) {
        float v2 = vred[j]; int k2 = kred[j];
        if (v2 < fv || (v2 == fv && k2 < fk)) { fv = v2; fk = k2; }
      }
      codes_out[n] = (float)fk;
    }
  }
}

__global__ void gather_loss_kernel(const float* __restrict__ z,
                                   const float* __restrict__ cb,
                                   float* __restrict__ out,
                                   const float* __restrict__ codes_f,
                                   double* __restrict__ loss_slots) {
  int gid = blockIdx.x * 256 + threadIdx.x;
  int n   = gid >> 6;
  int d4  = (gid & 63) * 4;
  int c   = (int)codes_f[n];
  float4 q  = *(const float4*)(cb + (size_t)c * DIM + d4);
  float4 zv = *(const float4*)(z + (size_t)gid * 4);
  *(float4*)(out + (size_t)gid * 4) = q;
  float dx = q.x - zv.x, dy = q.y - zv.y, dz = q.z - zv.z, dw = q.w - zv.w;
  float s = dx * dx + dy * dy + dz * dz + dw * dw;
#pragma unroll
  for (int off = 32; off > 0; off >>= 1) s += __shfl_down(s, off);
  __shared__ float wsum[4];
  int lane = threadIdx.x & 63, wv = threadIdx.x >> 6;
  if (lane == 0) wsum[wv] = s;
  __syncthreads();
  if (threadIdx.x == 0) {
    float tot = wsum[0] + wsum[1] + wsum[2] + wsum[3];
    atomicAdd(&loss_slots[blockIdx.x & 255], (double)tot);
  }
}

__global__ void finalize_kernel(const double* __restrict__ loss_slots,
                                float* __restrict__ out_loss) {
  double s = 0.0;
  for (int i = 0; i < 256; ++i) s += loss_slots[i];
  out_loss[0] = (float)(1.25 * s / (double)(N_PTS * (size_t)DIM));
}

extern "C" void kernel_launch(void* const* d_in, const int* in_sizes, int n_in,
                              void* d_out, int out_size, void* d_ws, size_t ws_size,
                              hipStream_t stream) {
  const float* z  = (const float*)d_in[0];
  const float* cb = (const float*)d_in[1];
  float* out = (float*)d_out;
  double* loss_slots = (double*)d_ws;
  int*   flag_count  = (int*)((char*)d_ws + 2048);
  float* Bf          = (float*)((char*)d_ws + 4096);
  int*   flag_list   = (int*)((char*)d_ws + 8192);
  short* cbh_perm    = (short*)d_out;            // scratch in out[0:524288)
  short* cbl_perm    = (short*)d_out + 262144;   // scratch in out[524288:1048576)

  hipMemsetAsync(d_ws, 0, 4096, stream);
  prep_cb_kernel<<<K_CODES / 4, 256, 0, stream>>>(cb, cbh_perm, cbl_perm, Bf);
  argmin_mfma_kernel<<<N_PTS / 64, 256, 0, stream>>>(
      z, cbh_perm, cbl_perm, Bf, out + OUT_VALS, flag_count, flag_list);
  fixup_kernel<<<2048, 256, 0, stream>>>(z, cb, Bf, flag_list, flag_count,
                                         out + OUT_VALS);
  gather_loss_kernel<<<(N_PTS * DIM / 4) / 256, 256, 0, stream>>>(
      z, cb, out, out + OUT_VALS, loss_slots);
  finalize_kernel<<<1, 1, 0, stream>>>(loss_slots, out + OUT_VALS + OUT_CODES);
}

// Round 2
// 300.237 us; speedup vs baseline: 2.5597x; 1.4279x over previous
//
#include <hip/hip_runtime.h>

// VQ-VAE vector quantizer, MI355X (gfx950).
// Round 7: kill the full-codebook fixup rescan (was DS-pipe bound: 12
// ds_bpermute per code for the fp64 butterfly, ~186us).
//  - pass A now tracks top-3 values + second-best index (cost ~1% of the
//    MFMA work per step).
//  - gap2 < MARGIN <= gap3  ->  true argmin provably in {bestk, seck}:
//    fixup_pair evaluates exactly 2 codes per row (one wave/row).
//    Safety: 2*(emul rounding 3.1e-5 + bf16-path 2e-6) = 6.6e-5 < 1e-4.
//  - gap3 < MARGIN (expected ~15-50 rows) -> fixup_full rescans 1024 codes,
//    4 blocks/row, merged via atomicMin on packed (f32-bits<<32 | k).
//
// d_out (float32): [0,16777216) quantized; [16777216,16842752) codes; [16842752] vq_loss
//   scratch (all overwritten by gather later):
//     bytes [0, 1048576)        cbh_perm | cbl_perm
//     bytes [1048576, 1572864)  ull minkey scratch[65536] (memset 0xFF)
//     bytes [1572864, 1835008)  int flagf[65536]
// d_ws: [0,2048) double loss_slots[256]; [2048,2052) int cnt2; [2052,2056) int cntf;
//       [4096,8192) float Bf[1024]; [8192,270336) uint flag2[65536] (n | seck<<16)

#define N_PTS    65536
#define K_CODES  1024
#define DIM      256
#define MARGIN   1.0e-4f

#define OUT_VALS  16777216
#define OUT_CODES 65536

typedef __attribute__((ext_vector_type(8))) short short8v;
typedef __attribute__((ext_vector_type(4))) float float4v;

__device__ __forceinline__ short f2bf(float x) {
  union { float f; unsigned u; } v; v.f = x;
  unsigned r = v.u + 0x7fff + ((v.u >> 16) & 1);   // RTN-even
  return (short)(r >> 16);
}
__device__ __forceinline__ float bf2f(short h) {
  union { unsigned u; float f; } v; v.u = ((unsigned)(unsigned short)h) << 16;
  return v.f;
}

// perm index (in shorts) for codebook element (r, k):
// chunk = ((r>>4)*8 + (k>>5))*4 + ((k>>3)&3); idx = chunk*128 + (r&15)*8 + (k&7)
__device__ __forceinline__ int perm_idx(int r, int k) {
  return ((((r >> 4) * 8 + (k >> 5)) * 4 + ((k >> 3) & 3)) * 128) + (r & 15) * 8 + (k & 7);
}

// one wave per code row: Bf[r] = fl32(fp64 sum of squares); also emit bf16
// hi AND lo codebook splits in B-fragment-permuted order. grid 256 x 256.
__global__ void prep_cb_kernel(const float* __restrict__ cb,
                               short* __restrict__ cbh_perm,
                               short* __restrict__ cbl_perm,
                               float* __restrict__ Bf) {
  int r    = blockIdx.x * 4 + (threadIdx.x >> 6);
  int lane = threadIdx.x & 63;
  const float4 v = *(const float4*)(cb + (size_t)r * DIM + lane * 4);
  double s = (double)v.x * v.x + (double)v.y * v.y
           + (double)v.z * v.z + (double)v.w * v.w;
#pragma unroll
  for (int off = 32; off > 0; off >>= 1) s += __shfl_down(s, off);
  if (lane == 0) Bf[r] = (float)s;
  short4 h = make_short4(f2bf(v.x), f2bf(v.y), f2bf(v.z), f2bf(v.w));
  short4 lo = make_short4(f2bf(v.x - bf2f(h.x)), f2bf(v.y - bf2f(h.y)),
                          f2bf(v.z - bf2f(h.z)), f2bf(v.w - bf2f(h.w)));
  *(short4*)(cbh_perm + perm_idx(r, lane * 4)) = h;    // (k&7)∈{0,4}: 8B aligned
  *(short4*)(cbl_perm + perm_idx(r, lane * 4)) = lo;
}

// 1024 blocks x 256 thr (4 waves). Block: 64 points x all 1024 codes.
// Wave w: 16 points. A-frags resident (hi+lo). Codes iterated 32 at a time.
__global__ __launch_bounds__(256, 4) void argmin_mfma_kernel(
    const float* __restrict__ z, const short* __restrict__ cbh_perm,
    const short* __restrict__ cbl_perm,
    const float* __restrict__ Bf, float* __restrict__ codes_out,
    int* __restrict__ cnt2, int* __restrict__ cntf,
    unsigned* __restrict__ flag2, int* __restrict__ flagf) {
  __shared__ __align__(16) short lbuf[16384];  // 32 KB: 32 codes x 256 d, hi | lo
  const int t    = threadIdx.x;
  const int w    = t >> 6;
  const int l    = t & 63;
  const int quad = l >> 4;
  const int lr   = l & 15;
  const int m0   = blockIdx.x * 64;

  // A-fragments: lane holds A[m=lr][k=q*32+quad*8+j], split bf16 hi/lo
  short8v ah[8], al[8];
  {
    const float* zrow = z + (size_t)(m0 + w * 16 + lr) * DIM;
#pragma unroll
    for (int q = 0; q < 8; ++q) {
      float4 p0 = *(const float4*)(zrow + q * 32 + quad * 8);
      float4 p1 = *(const float4*)(zrow + q * 32 + quad * 8 + 4);
      float e[8] = {p0.x, p0.y, p0.z, p0.w, p1.x, p1.y, p1.z, p1.w};
      short8v h, lo;
#pragma unroll
      for (int j = 0; j < 8; ++j) {
        short hb = f2bf(e[j]);
        h[j]  = hb;
        lo[j] = f2bf(e[j] - bf2f(hb));
      }
      ah[q] = h; al[q] = lo;
    }
  }

  float bestv[4], secv[4], thirdv[4]; int bestk[4], seck[4];
#pragma unroll
  for (int r = 0; r < 4; ++r) {
    bestv[r] = 3.0e38f; secv[r] = 3.0e38f; thirdv[r] = 3.0e38f;
    bestk[r] = 0; seck[r] = 0;
  }

  for (int c0 = 0; c0 < K_CODES; c0 += 32) {
    __syncthreads();
    // stage 16KB hi + 16KB lo, contiguous (perm layout == LDS layout)
    const short* srch = cbh_perm + c0 * 256;
    const short* srcl = cbl_perm + c0 * 256;
#pragma unroll
    for (int i = 0; i < 4; ++i) {
      *(float4*)(lbuf + t * 8 + i * 2048) = *(const float4*)(srch + t * 8 + i * 2048);
      *(float4*)(lbuf + 8192 + t * 8 + i * 2048) = *(const float4*)(srcl + t * 8 + i * 2048);
    }
    __syncthreads();

#pragma unroll
    for (int st = 0; st < 2; ++st) {
      float4v acc = {0.f, 0.f, 0.f, 0.f};
#pragma unroll
      for (int q = 0; q < 8; ++q) {
        // B-frag: lane holds B[k=quad*8+j][n=lr] == cb[n][k] (B^T rows)
        short8v bh = *(const short8v*)(lbuf + (st * 8 + q) * 512 + quad * 128 + lr * 8);
        short8v bl = *(const short8v*)(lbuf + 8192 + (st * 8 + q) * 512 + quad * 128 + lr * 8);
        acc = __builtin_amdgcn_mfma_f32_16x16x32_bf16(al[q], bh, acc, 0, 0, 0);
        acc = __builtin_amdgcn_mfma_f32_16x16x32_bf16(ah[q], bl, acc, 0, 0, 0);
        acc = __builtin_amdgcn_mfma_f32_16x16x32_bf16(ah[q], bh, acc, 0, 0, 0);
      }
      const int k = c0 + st * 16 + lr;       // this lane's code (C col = lane&15)
      const float bk_ = Bf[k];
#pragma unroll
      for (int r = 0; r < 4; ++r) {          // C row = quad*4 + r (point)
        float v = fmaf(-2.0f, acc[r], bk_);
        bool lt1 = v < bestv[r];
        bool lt2 = v < secv[r];
        bool lt3 = v < thirdv[r];
        thirdv[r] = lt2 ? secv[r] : (lt3 ? v : thirdv[r]);
        seck[r]   = lt1 ? bestk[r] : (lt2 ? k : seck[r]);
        secv[r]   = lt1 ? bestv[r] : (lt2 ? v : secv[r]);
        bestk[r]  = lt1 ? k : bestk[r];
        bestv[r]  = lt1 ? v : bestv[r];
      }
    }
  }

  // top-3 merge across the 16 col-lanes of each quad (butterfly).
  // Merge of sorted triples A,B (A = winner): x1=a1; x2=min(a2,b1);
  // x3 = (a2<b1) ? min(a3,b1) : min(a2,b2).  b3 can never reach rank 3.
#pragma unroll
  for (int mask = 1; mask < 16; mask <<= 1) {
#pragma unroll
    for (int r = 0; r < 4; ++r) {
      float ov  = __shfl_xor(bestv[r], mask);
      float os  = __shfl_xor(secv[r], mask);
      float ot  = __shfl_xor(thirdv[r], mask);
      int   ok  = __shfl_xor(bestk[r], mask);
      int   osk = __shfl_xor(seck[r], mask);
      bool win = (ov < bestv[r]) || (ov == bestv[r] && ok < bestk[r]);
      float a1 = win ? ov : bestv[r], a2 = win ? os : secv[r], a3 = win ? ot : thirdv[r];
      int   a1k = win ? ok : bestk[r], a2k = win ? osk : seck[r];
      float b1 = win ? bestv[r] : ov, b2 = win ? secv[r] : os;
      int   b1k = win ? bestk[r] : ok;
      bool s2 = (a2 < b1) || (a2 == b1 && a2k < b1k);
      bestv[r] = a1; bestk[r] = a1k;
      secv[r] = s2 ? a2 : b1; seck[r] = s2 ? a2k : b1k;
      thirdv[r] = s2 ? fminf(a3, b1) : fminf(a2, b2);
    }
  }
  if (lr == 0) {
#pragma unroll
    for (int r = 0; r < 4; ++r) {
      int n = m0 + w * 16 + quad * 4 + r;
      codes_out[n] = (float)bestk[r];
      if (thirdv[r] - bestv[r] < MARGIN) {
        int pos = atomicAdd(cntf, 1);
        flagf[pos] = n;
      } else if (secv[r] - bestv[r] < MARGIN) {
        int pos = atomicAdd(cnt2, 1);
        flag2[pos] = (unsigned)n | ((unsigned)seck[r] << 16);
      }
    }
  }
}

// Pair fixup: one wave per flagged row; half-wave per candidate code.
// Exact emulation: v = fl32(fl32(Sfl + Bf[k]) - 2*fl32(dot64)); tie -> lower k.
__global__ __launch_bounds__(256) void fixup_pair_kernel(
    const float* __restrict__ z, const float* __restrict__ cb,
    const float* __restrict__ Bf, const unsigned* __restrict__ flag2,
    const int* __restrict__ cnt2, float* __restrict__ codes_out) {
  const int t   = threadIdx.x;
  const int l   = t & 63;
  const int h   = l >> 5;          // 0 -> bestk, 1 -> seck
  const int sub = l & 31;          // dims sub*8 .. sub*8+7
  const int wid = blockIdx.x * 4 + (t >> 6);
  const int nw  = gridDim.x * 4;
  const int cnt = *cnt2;
  for (int i = wid; i < cnt; i += nw) {
    const unsigned rec = flag2[i];
    const int n  = rec & 0xFFFF;
    const int k2 = rec >> 16;
    const int k1 = (int)codes_out[n];
    const int k  = h ? k2 : k1;
    const float* zr = z + (size_t)n * DIM + sub * 8;
    const float* cr = cb + (size_t)k * DIM + sub * 8;
    const float4 za = *(const float4*)(zr);
    const float4 zb = *(const float4*)(zr + 4);
    const float4 ca = *(const float4*)(cr);
    const float4 cv = *(const float4*)(cr + 4);
    double s = (double)za.x*za.x + (double)za.y*za.y + (double)za.z*za.z + (double)za.w*za.w
             + (double)zb.x*zb.x + (double)zb.y*zb.y + (double)zb.z*zb.z + (double)zb.w*zb.w;
    double d = (double)za.x*ca.x + (double)za.y*ca.y + (double)za.z*ca.z + (double)za.w*ca.w
             + (double)zb.x*cv.x + (double)zb.y*cv.y + (double)zb.z*cv.z + (double)zb.w*cv.w;
#pragma unroll
    for (int m = 1; m < 32; m <<= 1) {
      s += __shfl_xor(s, m);
      d += __shfl_xor(d, m);
    }
    const float Sfl = (float)s;
    const float T1  = Sfl + Bf[k];
    const float v   = T1 - 2.0f * (float)d;
    const float vo  = __shfl_xor(v, 32);
    const int   ko  = __shfl_xor(k, 32);
    const bool keep = (v < vo) || (v == vo && k < ko);
    if (l == 0) codes_out[n] = (float)(keep ? k : ko);
  }
}

// Full rescan for rows with 3+ candidates inside MARGIN (expected ~tens).
// 4 blocks per row (quarter q = codes q*256..q*256+255); wave handles 64.
// Cross-block merge via atomicMin on (f32-bits<<32 | k); v>0 always
// (d ~ ||z||^2 ~ 100..500) so the uint order of the float bits is monotone.
__global__ __launch_bounds__(256) void fixup_full_kernel(
    const float* __restrict__ z, const float* __restrict__ cb,
    const float* __restrict__ Bf, const int* __restrict__ flagf,
    const int* __restrict__ cntf, unsigned long long* __restrict__ scratch) {
  __shared__ float vred[4];
  __shared__ int   kred[4];
  const int t = threadIdx.x;
  const int w = t >> 6;
  const int l = t & 63;
  const int cnt = *cntf;
  for (int ib = blockIdx.x; (ib >> 2) < cnt; ib += gridDim.x) {
    const int i = ib >> 2, q = ib & 3;
    const int n = flagf[i];
    const float4 zv = *(const float4*)(z + (size_t)n * DIM + l * 4);
    double s = (double)zv.x*zv.x + (double)zv.y*zv.y
             + (double)zv.z*zv.z + (double)zv.w*zv.w;
#pragma unroll
    for (int off = 32; off > 0; off >>= 1) s += __shfl_xor(s, off);
    const float Sfl = (float)s;
    float bv = 3.0e38f; int bk = 0;
    const int kbase = q * 256 + w * 64;
#pragma unroll 4
    for (int k0 = 0; k0 < 64; ++k0) {
      const int k = kbase + k0;
      const float4 cv = *(const float4*)(cb + (size_t)k * DIM + l * 4);
      double d = (double)zv.x*cv.x + (double)zv.y*cv.y
               + (double)zv.z*cv.z + (double)zv.w*cv.w;
#pragma unroll
      for (int off = 32; off > 0; off >>= 1) d += __shfl_xor(d, off);
      float T1 = Sfl + Bf[k];
      float v  = T1 - 2.0f * (float)d;
      if (v < bv) { bv = v; bk = k; }     // ascending k -> keeps lowest on tie
    }
    __syncthreads();
    if (l == 0) { vred[w] = bv; kred[w] = bk; }
    __syncthreads();
    if (t == 0) {
      float fv = vred[0]; int fk = kred[0];
#pragma unroll
      for (int j = 1; j < 4; ++j) {
        float v2 = vred[j]; int kk = kred[j];
        if (v2 < fv || (v2 == fv && kk < fk)) { fv = v2; fk = kk; }
      }
      unsigned long long key =
          ((unsigned long long)__float_as_uint(fv) << 32) | (unsigned)fk;
      atomicMin(&scratch[n], key);
    }
  }
}

__global__ void fixup_write_kernel(const int* __restrict__ flagf,
                                   const int* __restrict__ cntf,
                                   const unsigned long long* __restrict__ scratch,
                                   float* __restrict__ codes_out) {
  int i = blockIdx.x * 256 + threadIdx.x;
  if (i < *cntf) {
    int n = flagf[i];
    codes_out[n] = (float)(unsigned)(scratch[n] & 0xFFFFFFFFull);
  }
}

__global__ void gather_loss_kernel(const float* __restrict__ z,
                                   const float* __restrict__ cb,
                                   float* __restrict__ out,
                                   const float* __restrict__ codes_f,
                                   double* __restrict__ loss_slots) {
  int gid = blockIdx.x * 256 + threadIdx.x;
  int n   = gid >> 6;
  int d4  = (gid & 63) * 4;
  int c   = (int)codes_f[n];
  float4 q  = *(const float4*)(cb + (size_t)c * DIM + d4);
  float4 zv = *(const float4*)(z + (size_t)gid * 4);
  *(float4*)(out + (size_t)gid * 4) = q;
  float dx = q.x - zv.x, dy = q.y - zv.y, dz = q.z - zv.z, dw = q.w - zv.w;
  float s = dx * dx + dy * dy + dz * dz + dw * dw;
#pragma unroll
  for (int off = 32; off > 0; off >>= 1) s += __shfl_down(s, off);
  __shared__ float wsum[4];
  int lane = threadIdx.x & 63, wv = threadIdx.x >> 6;
  if (lane == 0) wsum[wv] = s;
  __syncthreads();
  if (threadIdx.x == 0) {
    float tot = wsum[0] + wsum[1] + wsum[2] + wsum[3];
    atomicAdd(&loss_slots[blockIdx.x & 255], (double)tot);
  }
}

__global__ void finalize_kernel(const double* __restrict__ loss_slots,
                                float* __restrict__ out_loss) {
  double s = 0.0;
  for (int i = 0; i < 256; ++i) s += loss_slots[i];
  out_loss[0] = (float)(1.25 * s / (double)(N_PTS * (size_t)DIM));
}

extern "C" void kernel_launch(void* const* d_in, const int* in_sizes, int n_in,
                              void* d_out, int out_size, void* d_ws, size_t ws_size,
                              hipStream_t stream) {
  const float* z  = (const float*)d_in[0];
  const float* cb = (const float*)d_in[1];
  float* out = (float*)d_out;
  double* loss_slots = (double*)d_ws;
  int*      cnt2  = (int*)((char*)d_ws + 2048);
  int*      cntf  = (int*)((char*)d_ws + 2052);
  float*    Bf    = (float*)((char*)d_ws + 4096);
  unsigned* flag2 = (unsigned*)((char*)d_ws + 8192);
  short* cbh_perm = (short*)d_out;            // scratch in out[0:524288) bytes
  short* cbl_perm = (short*)d_out + 262144;   // scratch in out[524288:1048576) bytes
  unsigned long long* scratch = (unsigned long long*)((char*)d_out + 1048576);
  int*   flagf    = (int*)((char*)d_out + 1572864);

  hipMemsetAsync(d_ws, 0, 4096, stream);
  hipMemsetAsync((char*)d_out + 1048576, 0xFF, 524288, stream);
  prep_cb_kernel<<<K_CODES / 4, 256, 0, stream>>>(cb, cbh_perm, cbl_perm, Bf);
  argmin_mfma_kernel<<<N_PTS / 64, 256, 0, stream>>>(
      z, cbh_perm, cbl_perm, Bf, out + OUT_VALS, cnt2, cntf, flag2, flagf);
  fixup_pair_kernel<<<1024, 256, 0, stream>>>(z, cb, Bf, flag2, cnt2,
                                              out + OUT_VALS);
  fixup_full_kernel<<<2048, 256, 0, stream>>>(z, cb, Bf, flagf, cntf, scratch);
  fixup_write_kernel<<<256, 256, 0, stream>>>(flagf, cntf, scratch,
                                              out + OUT_VALS);
  gather_loss_kernel<<<(N_PTS * DIM / 4) / 256, 256, 0, stream>>>(
      z, cb, out, out + OUT_VALS, loss_slots);
  finalize_kernel<<<1, 1, 0, stream>>>(loss_slots, out + OUT_VALS + OUT_CODES);
}

// Round 3
// 227.086 us; speedup vs baseline: 3.3842x; 1.3221x over previous
//
#include <hip/hip_runtime.h>

// VQ-VAE vector quantizer, MI355X (gfx950).
// Round 8: argmin pass A -> single fp16 MFMA pass (was bf16 hi/lo x3).
//  - Codebook pre-scaled by 2^10 (exact) into fp16: c' in (-1,1), no denormal
//    flush risk; per-term rounding <= |z c| 2^-10, 256-term random sum sigma
//    ~2e-6 -> pass err <= ~4e-5 (20 sigma). MARGIN 1.5e-4 > 2*(4e-5 + 3.06e-5
//    ref-emulation rounding) -> flag logic stays worst-case-safe for the data.
//  - Kills the 37 MB/dispatch scratch spill (A-frags now 32 VGPRs, total ~86:
//    fits; round-7 had 64 VGPR alloc + 144 B/thread spill).
//  - Halves LDS staging + B-frag read traffic (16 KB tile, 16 reads/iter).
//  - v = Bf[k] - 2*acc/1024 = fmaf(-2^-9, acc, Bf[k]) (exact scale fold).
//
// d_out (float32): [0,16777216) quantized; [16777216,16842752) codes; [16842752] vq_loss
//   scratch (all overwritten by gather later):
//     bytes [0, 524288)         cbh_perm (fp16, x1024)
//     bytes [1048576, 1572864)  ull minkey scratch[65536] (memset 0xFF)
//     bytes [1572864, 1835008)  int flagf[65536]
// d_ws: [0,2048) double loss_slots[256]; [2048,2052) int cnt2; [2052,2056) int cntf;
//       [4096,8192) float Bf[1024]; [8192,270336) uint flag2[65536] (n | seck<<16)

#define N_PTS    65536
#define K_CODES  1024
#define DIM      256
#define MARGIN   1.5e-4f

#define OUT_VALS  16777216
#define OUT_CODES 65536

typedef __attribute__((ext_vector_type(8))) short short8v;
typedef __attribute__((ext_vector_type(8))) _Float16 half8v;
typedef __attribute__((ext_vector_type(4))) float float4v;

// perm index (in shorts) for codebook element (r, k):
// chunk = ((r>>4)*8 + (k>>5))*4 + ((k>>3)&3); idx = chunk*128 + (r&15)*8 + (k&7)
__device__ __forceinline__ int perm_idx(int r, int k) {
  return ((((r >> 4) * 8 + (k >> 5)) * 4 + ((k >> 3) & 3)) * 128) + (r & 15) * 8 + (k & 7);
}

__device__ __forceinline__ short f2h_bits(float x) {
  union { _Float16 h; short s; } u;
  u.h = (_Float16)x;              // v_cvt_f16_f32, RTE
  return u.s;
}

// one wave per code row: Bf[r] = fl32(fp64 sum of squares of ORIGINAL cb);
// also emit fp16(1024*cb) in B-fragment-permuted order. grid 256 x 256.
__global__ void prep_cb_kernel(const float* __restrict__ cb,
                               short* __restrict__ cbh_perm,
                               float* __restrict__ Bf) {
  int r    = blockIdx.x * 4 + (threadIdx.x >> 6);
  int lane = threadIdx.x & 63;
  const float4 v = *(const float4*)(cb + (size_t)r * DIM + lane * 4);
  double s = (double)v.x * v.x + (double)v.y * v.y
           + (double)v.z * v.z + (double)v.w * v.w;
#pragma unroll
  for (int off = 32; off > 0; off >>= 1) s += __shfl_down(s, off);
  if (lane == 0) Bf[r] = (float)s;
  short4 h = make_short4(f2h_bits(v.x * 1024.0f), f2h_bits(v.y * 1024.0f),
                         f2h_bits(v.z * 1024.0f), f2h_bits(v.w * 1024.0f));
  *(short4*)(cbh_perm + perm_idx(r, lane * 4)) = h;   // (k&7)∈{0,4}: 8B aligned
}

// 1024 blocks x 256 thr (4 waves). Block: 64 points x all 1024 codes.
// Wave w: 16 points. A-frags resident (fp16). Codes iterated 32 at a time.
__global__ __launch_bounds__(256, 4) void argmin_mfma_kernel(
    const float* __restrict__ z, const short* __restrict__ cbh_perm,
    const float* __restrict__ Bf, float* __restrict__ codes_out,
    int* __restrict__ cnt2, int* __restrict__ cntf,
    unsigned* __restrict__ flag2, int* __restrict__ flagf) {
  __shared__ __align__(16) short lbuf[8192];   // 16 KB: 32 codes x 256 d, frag order
  const int t    = threadIdx.x;
  const int w    = t >> 6;
  const int l    = t & 63;
  const int quad = l >> 4;
  const int lr   = l & 15;
  const int m0   = blockIdx.x * 64;

  // A-fragments: lane holds A[m=lr][k=q*32+quad*8+j], fp16 (z unscaled)
  half8v ah[8];
  {
    const float* zrow = z + (size_t)(m0 + w * 16 + lr) * DIM;
#pragma unroll
    for (int q = 0; q < 8; ++q) {
      float4 p0 = *(const float4*)(zrow + q * 32 + quad * 8);
      float4 p1 = *(const float4*)(zrow + q * 32 + quad * 8 + 4);
      half8v h;
      h[0] = (_Float16)p0.x; h[1] = (_Float16)p0.y;
      h[2] = (_Float16)p0.z; h[3] = (_Float16)p0.w;
      h[4] = (_Float16)p1.x; h[5] = (_Float16)p1.y;
      h[6] = (_Float16)p1.z; h[7] = (_Float16)p1.w;
      ah[q] = h;
    }
  }

  float bestv[4], secv[4], thirdv[4]; int bestk[4], seck[4];
#pragma unroll
  for (int r = 0; r < 4; ++r) {
    bestv[r] = 3.0e38f; secv[r] = 3.0e38f; thirdv[r] = 3.0e38f;
    bestk[r] = 0; seck[r] = 0;
  }

  for (int c0 = 0; c0 < K_CODES; c0 += 32) {
    __syncthreads();
    // stage 16KB contiguous (perm layout == LDS layout)
    const short* src = cbh_perm + c0 * 256;
#pragma unroll
    for (int i = 0; i < 4; ++i)
      *(float4*)(lbuf + t * 8 + i * 2048) = *(const float4*)(src + t * 8 + i * 2048);
    __syncthreads();

#pragma unroll
    for (int st = 0; st < 2; ++st) {
      float4v acc = {0.f, 0.f, 0.f, 0.f};
#pragma unroll
      for (int q = 0; q < 8; ++q) {
        // B-frag: lane holds B[k=quad*8+j][n=lr] == cb'[n][k] (B^T rows)
        half8v b = *(const half8v*)(lbuf + (st * 8 + q) * 512 + quad * 128 + lr * 8);
        acc = __builtin_amdgcn_mfma_f32_16x16x32_f16(ah[q], b, acc, 0, 0, 0);
      }
      const int k = c0 + st * 16 + lr;       // this lane's code (C col = lane&15)
      const float bk_ = Bf[k];
#pragma unroll
      for (int r = 0; r < 4; ++r) {          // C row = quad*4 + r (point)
        float v = fmaf(-0.001953125f, acc[r], bk_);   // -2/1024, exact
        bool lt1 = v < bestv[r];
        bool lt2 = v < secv[r];
        bool lt3 = v < thirdv[r];
        thirdv[r] = lt2 ? secv[r] : (lt3 ? v : thirdv[r]);
        seck[r]   = lt1 ? bestk[r] : (lt2 ? k : seck[r]);
        secv[r]   = lt1 ? bestv[r] : (lt2 ? v : secv[r]);
        bestk[r]  = lt1 ? k : bestk[r];
        bestv[r]  = lt1 ? v : bestv[r];
      }
    }
  }

  // top-3 merge across the 16 col-lanes of each quad (butterfly).
  // Merge of sorted triples A,B (A = winner): x1=a1; x2=min(a2,b1);
  // x3 = (a2<b1) ? min(a3,b1) : min(a2,b2).  b3 can never reach rank 3.
#pragma unroll
  for (int mask = 1; mask < 16; mask <<= 1) {
#pragma unroll
    for (int r = 0; r < 4; ++r) {
      float ov  = __shfl_xor(bestv[r], mask);
      float os  = __shfl_xor(secv[r], mask);
      float ot  = __shfl_xor(thirdv[r], mask);
      int   ok  = __shfl_xor(bestk[r], mask);
      int   osk = __shfl_xor(seck[r], mask);
      bool win = (ov < bestv[r]) || (ov == bestv[r] && ok < bestk[r]);
      float a1 = win ? ov : bestv[r], a2 = win ? os : secv[r], a3 = win ? ot : thirdv[r];
      int   a1k = win ? ok : bestk[r], a2k = win ? osk : seck[r];
      float b1 = win ? bestv[r] : ov, b2 = win ? secv[r] : os;
      int   b1k = win ? bestk[r] : ok;
      bool s2 = (a2 < b1) || (a2 == b1 && a2k < b1k);
      bestv[r] = a1; bestk[r] = a1k;
      secv[r] = s2 ? a2 : b1; seck[r] = s2 ? a2k : b1k;
      thirdv[r] = s2 ? fminf(a3, b1) : fminf(a2, b2);
    }
  }
  if (lr == 0) {
#pragma unroll
    for (int r = 0; r < 4; ++r) {
      int n = m0 + w * 16 + quad * 4 + r;
      codes_out[n] = (float)bestk[r];
      if (thirdv[r] - bestv[r] < MARGIN) {
        int pos = atomicAdd(cntf, 1);
        flagf[pos] = n;
      } else if (secv[r] - bestv[r] < MARGIN) {
        int pos = atomicAdd(cnt2, 1);
        flag2[pos] = (unsigned)n | ((unsigned)seck[r] << 16);
      }
    }
  }
}

// Pair fixup: one wave per flagged row; half-wave per candidate code.
// Exact emulation: v = fl32(fl32(Sfl + Bf[k]) - 2*fl32(dot64)); tie -> lower k.
__global__ __launch_bounds__(256) void fixup_pair_kernel(
    const float* __restrict__ z, const float* __restrict__ cb,
    const float* __restrict__ Bf, const unsigned* __restrict__ flag2,
    const int* __restrict__ cnt2, float* __restrict__ codes_out) {
  const int t   = threadIdx.x;
  const int l   = t & 63;
  const int h   = l >> 5;          // 0 -> bestk, 1 -> seck
  const int sub = l & 31;          // dims sub*8 .. sub*8+7
  const int wid = blockIdx.x * 4 + (t >> 6);
  const int nw  = gridDim.x * 4;
  const int cnt = *cnt2;
  for (int i = wid; i < cnt; i += nw) {
    const unsigned rec = flag2[i];
    const int n  = rec & 0xFFFF;
    const int k2 = rec >> 16;
    const int k1 = (int)codes_out[n];
    const int k  = h ? k2 : k1;
    const float* zr = z + (size_t)n * DIM + sub * 8;
    const float* cr = cb + (size_t)k * DIM + sub * 8;
    const float4 za = *(const float4*)(zr);
    const float4 zb = *(const float4*)(zr + 4);
    const float4 ca = *(const float4*)(cr);
    const float4 cv = *(const float4*)(cr + 4);
    double s = (double)za.x*za.x + (double)za.y*za.y + (double)za.z*za.z + (double)za.w*za.w
             + (double)zb.x*zb.x + (double)zb.y*zb.y + (double)zb.z*zb.z + (double)zb.w*zb.w;
    double d = (double)za.x*ca.x + (double)za.y*ca.y + (double)za.z*ca.z + (double)za.w*ca.w
             + (double)zb.x*cv.x + (double)zb.y*cv.y + (double)zb.z*cv.z + (double)zb.w*cv.w;
#pragma unroll
    for (int m = 1; m < 32; m <<= 1) {
      s += __shfl_xor(s, m);
      d += __shfl_xor(d, m);
    }
    const float Sfl = (float)s;
    const float T1  = Sfl + Bf[k];
    const float v   = T1 - 2.0f * (float)d;
    const float vo  = __shfl_xor(v, 32);
    const int   ko  = __shfl_xor(k, 32);
    const bool keep = (v < vo) || (v == vo && k < ko);
    if (l == 0) codes_out[n] = (float)(keep ? k : ko);
  }
}

// Full rescan for rows with 3+ candidates inside MARGIN (expected ~tens).
// 4 blocks per row (quarter q = codes q*256..q*256+255); wave handles 64.
// Cross-block merge via atomicMin on (f32-bits<<32 | k); v>0 always
// (d ~ ||z||^2 ~ 100..500) so the uint order of the float bits is monotone.
__global__ __launch_bounds__(256) void fixup_full_kernel(
    const float* __restrict__ z, const float* __restrict__ cb,
    const float* __restrict__ Bf, const int* __restrict__ flagf,
    const int* __restrict__ cntf, unsigned long long* __restrict__ scratch) {
  __shared__ float vred[4];
  __shared__ int   kred[4];
  const int t = threadIdx.x;
  const int w = t >> 6;
  const int l = t & 63;
  const int cnt = *cntf;
  for (int ib = blockIdx.x; (ib >> 2) < cnt; ib += gridDim.x) {
    const int i = ib >> 2, q = ib & 3;
    const int n = flagf[i];
    const float4 zv = *(const float4*)(z + (size_t)n * DIM + l * 4);
    double s = (double)zv.x*zv.x + (double)zv.y*zv.y
             + (double)zv.z*zv.z + (double)zv.w*zv.w;
#pragma unroll
    for (int off = 32; off > 0; off >>= 1) s += __shfl_xor(s, off);
    const float Sfl = (float)s;
    float bv = 3.0e38f; int bk = 0;
    const int kbase = q * 256 + w * 64;
#pragma unroll 4
    for (int k0 = 0; k0 < 64; ++k0) {
      const int k = kbase + k0;
      const float4 cv = *(const float4*)(cb + (size_t)k * DIM + l * 4);
      double d = (double)zv.x*cv.x + (double)zv.y*cv.y
               + (double)zv.z*cv.z + (double)zv.w*cv.w;
#pragma unroll
      for (int off = 32; off > 0; off >>= 1) d += __shfl_xor(d, off);
      float T1 = Sfl + Bf[k];
      float v  = T1 - 2.0f * (float)d;
      if (v < bv) { bv = v; bk = k; }     // ascending k -> keeps lowest on tie
    }
    __syncthreads();
    if (l == 0) { vred[w] = bv; kred[w] = bk; }
    __syncthreads();
    if (t == 0) {
      float fv = vred[0]; int fk = kred[0];
#pragma unroll
      for (int j = 1; j < 4; ++j) {
        float v2 = vred[j]; int kk = kred[j];
        if (v2 < fv || (v2 == fv && kk < fk)) { fv = v2; fk = kk; }
      }
      unsigned long long key =
          ((unsigned long long)__float_as_uint(fv) << 32) | (unsigned)fk;
      atomicMin(&scratch[n], key);
    }
  }
}

__global__ void fixup_write_kernel(const int* __restrict__ flagf,
                                   const int* __restrict__ cntf,
                                   const unsigned long long* __restrict__ scratch,
                                   float* __restrict__ codes_out) {
  int i = blockIdx.x * 256 + threadIdx.x;
  if (i < *cntf) {
    int n = flagf[i];
    codes_out[n] = (float)(unsigned)(scratch[n] & 0xFFFFFFFFull);
  }
}

__global__ void gather_loss_kernel(const float* __restrict__ z,
                                   const float* __restrict__ cb,
                                   float* __restrict__ out,
                                   const float* __restrict__ codes_f,
                                   double* __restrict__ loss_slots) {
  int gid = blockIdx.x * 256 + threadIdx.x;
  int n   = gid >> 6;
  int d4  = (gid & 63) * 4;
  int c   = (int)codes_f[n];
  float4 q  = *(const float4*)(cb + (size_t)c * DIM + d4);
  float4 zv = *(const float4*)(z + (size_t)gid * 4);
  *(float4*)(out + (size_t)gid * 4) = q;
  float dx = q.x - zv.x, dy = q.y - zv.y, dz = q.z - zv.z, dw = q.w - zv.w;
  float s = dx * dx + dy * dy + dz * dz + dw * dw;
#pragma unroll
  for (int off = 32; off > 0; off >>= 1) s += __shfl_down(s, off);
  __shared__ float wsum[4];
  int lane = threadIdx.x & 63, wv = threadIdx.x >> 6;
  if (lane == 0) wsum[wv] = s;
  __syncthreads();
  if (threadIdx.x == 0) {
    float tot = wsum[0] + wsum[1] + wsum[2] + wsum[3];
    atomicAdd(&loss_slots[blockIdx.x & 255], (double)tot);
  }
}

__global__ void finalize_kernel(const double* __restrict__ loss_slots,
                                float* __restrict__ out_loss) {
  double s = 0.0;
  for (int i = 0; i < 256; ++i) s += loss_slots[i];
  out_loss[0] = (float)(1.25 * s / (double)(N_PTS * (size_t)DIM));
}

extern "C" void kernel_launch(void* const* d_in, const int* in_sizes, int n_in,
                              void* d_out, int out_size, void* d_ws, size_t ws_size,
                              hipStream_t stream) {
  const float* z  = (const float*)d_in[0];
  const float* cb = (const float*)d_in[1];
  float* out = (float*)d_out;
  double* loss_slots = (double*)d_ws;
  int*      cnt2  = (int*)((char*)d_ws + 2048);
  int*      cntf  = (int*)((char*)d_ws + 2052);
  float*    Bf    = (float*)((char*)d_ws + 4096);
  unsigned* flag2 = (unsigned*)((char*)d_ws + 8192);
  short* cbh_perm = (short*)d_out;            // scratch in out[0:524288) bytes
  unsigned long long* scratch = (unsigned long long*)((char*)d_out + 1048576);
  int*   flagf    = (int*)((char*)d_out + 1572864);

  hipMemsetAsync(d_ws, 0, 4096, stream);
  hipMemsetAsync((char*)d_out + 1048576, 0xFF, 524288, stream);
  prep_cb_kernel<<<K_CODES / 4, 256, 0, stream>>>(cb, cbh_perm, Bf);
  argmin_mfma_kernel<<<N_PTS / 64, 256, 0, stream>>>(
      z, cbh_perm, Bf, out + OUT_VALS, cnt2, cntf, flag2, flagf);
  fixup_pair_kernel<<<1024, 256, 0, stream>>>(z, cb, Bf, flag2, cnt2,
                                              out + OUT_VALS);
  fixup_full_kernel<<<2048, 256, 0, stream>>>(z, cb, Bf, flagf, cntf, scratch);
  fixup_write_kernel<<<256, 256, 0, stream>>>(flagf, cntf, scratch,
                                              out + OUT_VALS);
  gather_loss_kernel<<<(N_PTS * DIM / 4) / 256, 256, 0, stream>>>(
      z, cb, out, out + OUT_VALS, loss_slots);
  finalize_kernel<<<1, 1, 0, stream>>>(loss_slots, out + OUT_VALS + OUT_CODES);
}